// Round 1
// baseline (503.911 us; speedup 1.0000x reference)
//
#include <hip/hip_runtime.h>

#define Bn 8
#define Qn 300
#define Pn 5
#define RSn 256
#define QSn 768
#define MTOT 10880
#define THRL -1.3862943611198906f   // log(0.2/0.8): sigmoid(x)>0.2 <=> x>THRL

__device__ inline float wred(float v){
  #pragma unroll
  for (int off = 32; off; off >>= 1) v += __shfl_xor(v, off);
  return v;
}

// ---- detect mask storage: det[0]!=0 => not int32{0,1}; det[1]!=0 => not f32{0,1.0}
__global__ void k_detect(const int* __restrict__ m0, int* det){
  int i = blockIdx.x * 256 + threadIdx.x;   // 8192 ints = 32KB, safe under all layouts
  int v = m0[i];
  if (v != 0 && v != 1) atomicOr(&det[0], 1);
  if (v != 0 && v != 0x3F800000) atomicOr(&det[1], 1);
}

// ---- query pooling: pooled[b,p,:] , flags[b,p] = cnt>0
__global__ void k_pooled(const float* __restrict__ pl, const float* __restrict__ hs,
                         float* pooled, int* flags){
  int b = blockIdx.x / Pn, p = blockIdx.x % Pn;
  int d = threadIdx.x;
  float ssum = 0.f, cnt = 0.f;
  for (int q = 0; q < Qn; ++q){
    float v = pl[(b*Qn + q)*Pn + p];
    if (v > THRL){ cnt += 1.f; ssum += hs[(b*Qn + q)*RSn + d]; }  // uniform branch
  }
  pooled[(b*Pn + p)*RSn + d] = (cnt > 0.f) ? ssum / cnt : 0.f;
  if (d == 0) flags[b*Pn + p] = (cnt > 0.f) ? 1 : 0;
}

// ---- query tokens + LN -> qt[b,6,768]
__global__ void k_qtok(const float* __restrict__ lq, const float* __restrict__ Wq,
                       const float* __restrict__ bq, const float* __restrict__ qng,
                       const float* __restrict__ qnb, const float* __restrict__ pooled,
                       const int* __restrict__ flags, float* qt){
  __shared__ float s1[4], s2[4];
  int b = blockIdx.x / 6, j = blockIdx.x % 6;
  int t = threadIdx.x;
  float v0 = lq[j*QSn + t], v1 = lq[j*QSn + t + 256], v2 = lq[j*QSn + t + 512];
  int any = flags[b*Pn] | flags[b*Pn+1] | flags[b*Pn+2] | flags[b*Pn+3] | flags[b*Pn+4];
  if (j > 0 && any){
    const float* pp = pooled + (b*Pn + (j-1))*RSn;
    float a0 = 0.f, a1 = 0.f, a2 = 0.f;
    for (int c = 0; c < RSn; ++c){
      float pv = pp[c];
      a0 = fmaf(pv, Wq[c*QSn + t      ], a0);
      a1 = fmaf(pv, Wq[c*QSn + t + 256], a1);
      a2 = fmaf(pv, Wq[c*QSn + t + 512], a2);
    }
    v0 += a0 + bq[t]; v1 += a1 + bq[t+256]; v2 += a2 + bq[t+512];
  }
  float sm = v0 + v1 + v2, sq = v0*v0 + v1*v1 + v2*v2;
  sm = wred(sm); sq = wred(sq);
  int wid = t >> 6, lane = t & 63;
  if (lane == 0){ s1[wid] = sm; s2[wid] = sq; }
  __syncthreads();
  float S  = s1[0] + s1[1] + s1[2] + s1[3];
  float SQ = s2[0] + s2[1] + s2[2] + s2[3];
  float mu = S * (1.f/QSn), var = SQ * (1.f/QSn) - mu*mu;
  float rs = rsqrtf(var + 1e-5f);
  float* o = qt + (b*6 + j)*QSn;
  o[t      ] = (v0 - mu)*rs*qng[t      ] + qnb[t      ];
  o[t + 256] = (v1 - mu)*rs*qng[t + 256] + qnb[t + 256];
  o[t + 512] = (v2 - mu)*rs*qng[t + 512] + qnb[t + 512];
}

// ---- pool (feat+pos)*(1-mask) 2x2 -> AT[k=256][m=10880] (already /mp), invmp[m]
__global__ void k_pool(const float* f0, const float* p0, const void* m0,
                       const float* f1, const float* p1, const void* m1,
                       const float* f2, const float* p2, const void* m2,
                       const float* f3, const float* p3, const void* m3,
                       const int* __restrict__ det, float* AT, float* invmp){
  int bx = blockIdx.x;
  int s = bx >> 11, b = (bx >> 8) & 7, c = bx & 255;
  const float* F; const float* Pp; const void* M; int H, SB;
  if (s == 0){ F=f0; Pp=p0; M=m0; H=64; SB=0;     }
  else if (s == 1){ F=f1; Pp=p1; M=m1; H=32; SB=8192;  }
  else if (s == 2){ F=f2; Pp=p2; M=m2; H=16; SB=10240; }
  else            { F=f3; Pp=p3; M=m3; H=8;  SB=10752; }
  int OW = H >> 1, T = OW * OW;
  int mode = (det[0] == 0) ? 0 : ((det[1] == 0) ? 2 : 1);
  const float* Fb = F + (size_t)(b*256 + c)*H*H;
  const float* Pb = Pp + (size_t)(b*256 + c)*H*H;
  int mbase = b*H*H;
  for (int tok = threadIdx.x; tok < T; tok += 256){
    int ph = tok / OW, pw = tok - ph*OW;
    int i00 = (ph*2)*H + pw*2;
    float xs = 0.f, msum = 0.f;
    #pragma unroll
    for (int dr = 0; dr < 2; ++dr){
      #pragma unroll
      for (int dc = 0; dc < 2; ++dc){
        int i = i00 + dr*H + dc;
        float mk;
        if (mode == 0)      mk = ((const int*)M)[mbase + i] ? 1.f : 0.f;
        else if (mode == 1) mk = ((const unsigned char*)M)[mbase + i] ? 1.f : 0.f;
        else                mk = ((const float*)M)[mbase + i];
        float w = 1.f - mk;
        xs += (Fb[i] + Pb[i]) * w;
        msum += w;
      }
    }
    float mp = fmaxf(msum * 0.25f, 1e-6f);
    float im = 1.f / mp;
    int mIdx = SB + b*T + tok;
    AT[(size_t)c*MTOT + mIdx] = xs * 0.25f * im;
    if (c == 0) invmp[mIdx] = im;
  }
}

// ---- GEMM: P[m][n] = sum_k AT[k][m]*convW_s[n][k] + convb_s[n]*invmp[m]
__global__ __launch_bounds__(256) void k_gemm(const float* __restrict__ AT,
    const float* __restrict__ invmp,
    const float* cw0, const float* cb0, const float* cw1, const float* cb1,
    const float* cw2, const float* cb2, const float* cw3, const float* cb3,
    float* __restrict__ Pout){
  __shared__ float As[16][64];
  __shared__ float Bs[16][68];
  int mt = blockIdx.x / 12, nt = blockIdx.x % 12;
  int m0 = mt*64, n0 = nt*64;
  const float* CW; const float* CB;
  if (m0 < 8192){ CW=cw0; CB=cb0; }
  else if (m0 < 10240){ CW=cw1; CB=cb1; }
  else if (m0 < 10752){ CW=cw2; CB=cb2; }
  else { CW=cw3; CB=cb3; }
  int t = threadIdx.x;
  int tx = t & 15, ty = t >> 4;
  int am = t & 63, ak = t >> 6;
  int bn = t >> 2, bk4 = (t & 3)*4;
  float acc[4][4];
  #pragma unroll
  for (int i=0;i<4;++i)
    #pragma unroll
    for (int jj=0;jj<4;++jj) acc[i][jj] = 0.f;
  for (int kc = 0; kc < 256; kc += 16){
    #pragma unroll
    for (int i = 0; i < 4; ++i)
      As[ak + i*4][am] = AT[(size_t)(kc + ak + i*4)*MTOT + m0 + am];
    float4 w = *(const float4*)(CW + (size_t)(n0 + bn)*256 + kc + bk4);
    Bs[bk4+0][bn] = w.x; Bs[bk4+1][bn] = w.y; Bs[bk4+2][bn] = w.z; Bs[bk4+3][bn] = w.w;
    __syncthreads();
    #pragma unroll
    for (int k = 0; k < 16; ++k){
      float4 a4 = *(const float4*)(&As[k][tx*4]);
      float4 b4 = *(const float4*)(&Bs[k][ty*4]);
      float av[4] = {a4.x, a4.y, a4.z, a4.w};
      float bv[4] = {b4.x, b4.y, b4.z, b4.w};
      #pragma unroll
      for (int i = 0; i < 4; ++i)
        #pragma unroll
        for (int jj = 0; jj < 4; ++jj)
          acc[i][jj] = fmaf(av[i], bv[jj], acc[i][jj]);
    }
    __syncthreads();
  }
  #pragma unroll
  for (int i = 0; i < 4; ++i){
    int m = m0 + tx*4 + i;
    float im = invmp[m];
    float4 o;
    o.x = acc[i][0] + CB[n0 + ty*4 + 0]*im;
    o.y = acc[i][1] + CB[n0 + ty*4 + 1]*im;
    o.z = acc[i][2] + CB[n0 + ty*4 + 2]*im;
    o.w = acc[i][3] + CB[n0 + ty*4 + 3]*im;
    *(float4*)(Pout + (size_t)m*768 + n0 + ty*4) = o;
  }
}

// ---- per-token LN (wave per row) + accumulate sum over tokens into ctxsum[b][768]
__global__ void k_lnacc(const float* __restrict__ Pin,
    const float* lg0, const float* lb0, const float* lg1, const float* lb1,
    const float* lg2, const float* lb2, const float* lg3, const float* lb3,
    float* ctxsum){
  int bx = blockIdx.x;
  int s, b, m0, cnt;
  if (bx < 128){ s=0; b=bx>>4; m0 = b*1024 + (bx&15)*64; cnt=64; }
  else if (bx < 160){ int i=bx-128; s=1; b=i>>2; m0 = 8192 + b*256 + (i&3)*64; cnt=64; }
  else if (bx < 168){ s=2; b=bx-160; m0 = 10240 + b*64; cnt=64; }
  else { s=3; b=bx-168; m0 = 10752 + b*16; cnt=16; }
  const float* LG; const float* LB;
  if (s==0){LG=lg0;LB=lb0;} else if (s==1){LG=lg1;LB=lb1;}
  else if (s==2){LG=lg2;LB=lb2;} else {LG=lg3;LB=lb3;}
  int wid = threadIdx.x >> 6, lane = threadIdx.x & 63;
  float acc[12];
  #pragma unroll
  for (int j = 0; j < 12; ++j) acc[j] = 0.f;
  int rows = 0;
  for (int r = wid; r < cnt; r += 4){
    const float* row = Pin + (size_t)(m0 + r)*768;
    float x[12]; float sm = 0.f, sq = 0.f;
    #pragma unroll
    for (int j = 0; j < 12; ++j){
      x[j] = row[lane + 64*j];
      sm += x[j]; sq = fmaf(x[j], x[j], sq);
    }
    sm = wred(sm); sq = wred(sq);
    float mu = sm * (1.f/768.f);
    float var = sq * (1.f/768.f) - mu*mu;
    float rs = rsqrtf(var + 1e-5f);
    #pragma unroll
    for (int j = 0; j < 12; ++j) acc[j] += (x[j] - mu)*rs;
    rows++;
  }
  #pragma unroll
  for (int j = 0; j < 12; ++j){
    int n = lane + 64*j;
    atomicAdd(&ctxsum[b*768 + n], acc[j]*LG[n] + (float)rows*LB[n]);
  }
}

// ---- v = qt0 + 0.2*sum(qt1..5) + 2*ctxsum/1360
__global__ void k_v(const float* __restrict__ qt, const float* __restrict__ ctxsum, float* v){
  int idx = blockIdx.x*256 + threadIdx.x;   // 6144
  int b = idx / 768, n = idx % 768;
  const float* q = qt + (size_t)b*6*768;
  float pm = q[768+n] + q[2*768+n] + q[3*768+n] + q[4*768+n] + q[5*768+n];
  v[idx] = q[n] + 0.2f*pm + 2.f*ctxsum[b*768 + n]*(1.f/1360.f);
}

// ---- h = relu(v @ W1 + b1)
__global__ void k_h(const float* __restrict__ v, const float* __restrict__ W1,
                    const float* __restrict__ b1, float* h){
  int idx = blockIdx.x*256 + threadIdx.x;   // 6144
  int b = idx / 768, o = idx % 768;
  const float* vb = v + b*768;
  float acc = b1[o];
  for (int c = 0; c < 768; ++c) acc = fmaf(vb[c], W1[c*768 + o], acc);
  h[idx] = fmaxf(acc, 0.f);
}

// ---- out = h @ W2 + b2
__global__ void k_out(const float* __restrict__ h, const float* __restrict__ W2,
                      const float* __restrict__ b2, float* out){
  int b = blockIdx.x, o = threadIdx.x;
  if (o >= 396) return;
  const float* hb = h + b*768;
  float acc = b2[o];
  for (int c = 0; c < 768; ++c) acc = fmaf(hb[c], W2[c*396 + o], acc);
  out[b*396 + o] = acc;
}

extern "C" void kernel_launch(void* const* d_in, const int* in_sizes, int n_in,
                              void* d_out, int out_size, void* d_ws, size_t ws_size,
                              hipStream_t stream){
  const float* pl = (const float*)d_in[0];
  const float* hs = (const float*)d_in[2];
  const float* feat[4]; const float* pos[4]; const void* mask[4];
  const float* cw[4]; const float* cb[4]; const float* lg[4]; const float* lb[4];
  for (int s = 0; s < 4; ++s){
    int base = 3 + 7*s;
    feat[s] = (const float*)d_in[base];
    pos[s]  = (const float*)d_in[base+1];
    mask[s] = d_in[base+2];
    cw[s]   = (const float*)d_in[base+3];
    cb[s]   = (const float*)d_in[base+4];
    lg[s]   = (const float*)d_in[base+5];
    lb[s]   = (const float*)d_in[base+6];
  }
  const float* lq  = (const float*)d_in[31];
  const float* Wq  = (const float*)d_in[32];
  const float* bq  = (const float*)d_in[33];
  const float* qng = (const float*)d_in[34];
  const float* qnb = (const float*)d_in[35];
  const float* W1  = (const float*)d_in[36];
  const float* b1  = (const float*)d_in[37];
  const float* W2  = (const float*)d_in[38];
  const float* b2  = (const float*)d_in[39];
  float* out = (float*)d_out;

  float* AT     = (float*)d_ws;                 // 256*10880
  float* Pbuf   = AT + (size_t)256*MTOT;        // 10880*768
  float* invmp  = Pbuf + (size_t)MTOT*768;      // 10880
  float* pooled = invmp + MTOT;                 // 40*256
  float* qt     = pooled + 40*RSn;              // 8*6*768
  float* vv     = qt + Bn*6*QSn;                // 8*768
  float* hh     = vv + Bn*QSn;                  // 8*768
  float* ctxsum = hh + Bn*QSn;                  // 8*768
  int*   det    = (int*)(ctxsum + Bn*QSn);      // 4 ints
  int*   flags  = det + 4;                      // 40 ints

  hipMemsetAsync(ctxsum, 0, Bn*QSn*sizeof(float) + 4*sizeof(int), stream);
  k_detect<<<32, 256, 0, stream>>>((const int*)mask[0], det);
  k_pooled<<<Bn*Pn, 256, 0, stream>>>(pl, hs, pooled, flags);
  k_qtok<<<Bn*6, 256, 0, stream>>>(lq, Wq, bq, qng, qnb, pooled, flags, qt);
  k_pool<<<8192, 256, 0, stream>>>(feat[0], pos[0], mask[0],
                                   feat[1], pos[1], mask[1],
                                   feat[2], pos[2], mask[2],
                                   feat[3], pos[3], mask[3],
                                   det, AT, invmp);
  k_gemm<<<170*12, 256, 0, stream>>>(AT, invmp,
                                     cw[0], cb[0], cw[1], cb[1],
                                     cw[2], cb[2], cw[3], cb[3], Pbuf);
  k_lnacc<<<176, 256, 0, stream>>>(Pbuf, lg[0], lb[0], lg[1], lb[1],
                                   lg[2], lb[2], lg[3], lb[3], ctxsum);
  k_v<<<24, 256, 0, stream>>>(qt, ctxsum, vv);
  k_h<<<24, 256, 0, stream>>>(vv, W1, b1, hh);
  k_out<<<Bn, 512, 0, stream>>>(hh, W2, b2, out);
}

// Round 2
// 379.725 us; speedup vs baseline: 1.3270x; 1.3270x over previous
//
#include <hip/hip_runtime.h>
#include <hip/hip_bf16.h>

#define Bn 8
#define Qn 300
#define Pn 5
#define RSn 256
#define QSn 768
#define MTOT 10880
#define THRL -1.3862943611198906f   // log(0.2/0.8): sigmoid(x)>0.2 <=> x>THRL

typedef __attribute__((ext_vector_type(8))) short short8;
typedef __attribute__((ext_vector_type(4))) float float4v;

__device__ inline float wred(float v){
  #pragma unroll
  for (int off = 32; off; off >>= 1) v += __shfl_xor(v, off);
  return v;
}

// ---- detect mask storage: det[0]!=0 => not int32{0,1}; det[1]!=0 => not f32{0,1.0}
__global__ void k_detect(const int* __restrict__ m0, int* det){
  int i = blockIdx.x * 256 + threadIdx.x;   // 8192 ints = 32KB, safe under all layouts
  int v = m0[i];
  if (v != 0 && v != 1) atomicOr(&det[0], 1);
  if (v != 0 && v != 0x3F800000) atomicOr(&det[1], 1);
}

// ---- query pooling: pooled[b,p,:], flags[b,p] = cnt>0
// Phase 1: mask -> LDS (independent loads). Phase 2: unconditional FMA loop (pipelined).
__global__ void k_pooled(const float* __restrict__ pl, const float* __restrict__ hs,
                         float* pooled, int* flags){
  __shared__ float msk[Qn];
  int b = blockIdx.x / Pn, p = blockIdx.x % Pn;
  int t = threadIdx.x;
  for (int q = t; q < Qn; q += 256)
    msk[q] = (pl[(b*Qn + q)*Pn + p] > THRL) ? 1.f : 0.f;
  __syncthreads();
  const float* hb = hs + (size_t)b*Qn*RSn + t;
  float ssum = 0.f, cnt = 0.f;
  for (int q = 0; q < Qn; ++q){
    float m = msk[q];
    cnt += m;
    ssum = fmaf(m, hb[(size_t)q*RSn], ssum);
  }
  pooled[(b*Pn + p)*RSn + t] = (cnt > 0.f) ? ssum / cnt : 0.f;
  if (t == 0) flags[b*Pn + p] = (cnt > 0.f) ? 1 : 0;
}

// ---- query tokens + LN -> qt[b,6,768]
__global__ void k_qtok(const float* __restrict__ lq, const float* __restrict__ Wq,
                       const float* __restrict__ bq, const float* __restrict__ qng,
                       const float* __restrict__ qnb, const float* __restrict__ pooled,
                       const int* __restrict__ flags, float* qt){
  __shared__ float s1[4], s2[4];
  int b = blockIdx.x / 6, j = blockIdx.x % 6;
  int t = threadIdx.x;
  float v0 = lq[j*QSn + t], v1 = lq[j*QSn + t + 256], v2 = lq[j*QSn + t + 512];
  int any = flags[b*Pn] | flags[b*Pn+1] | flags[b*Pn+2] | flags[b*Pn+3] | flags[b*Pn+4];
  if (j > 0 && any){
    const float* pp = pooled + (b*Pn + (j-1))*RSn;
    float a0 = 0.f, a1 = 0.f, a2 = 0.f;
    for (int c = 0; c < RSn; ++c){
      float pv = pp[c];
      a0 = fmaf(pv, Wq[c*QSn + t      ], a0);
      a1 = fmaf(pv, Wq[c*QSn + t + 256], a1);
      a2 = fmaf(pv, Wq[c*QSn + t + 512], a2);
    }
    v0 += a0 + bq[t]; v1 += a1 + bq[t+256]; v2 += a2 + bq[t+512];
  }
  float sm = v0 + v1 + v2, sq = v0*v0 + v1*v1 + v2*v2;
  sm = wred(sm); sq = wred(sq);
  int wid = t >> 6, lane = t & 63;
  if (lane == 0){ s1[wid] = sm; s2[wid] = sq; }
  __syncthreads();
  float S  = s1[0] + s1[1] + s1[2] + s1[3];
  float SQ = s2[0] + s2[1] + s2[2] + s2[3];
  float mu = S * (1.f/QSn), var = SQ * (1.f/QSn) - mu*mu;
  float rs = rsqrtf(var + 1e-5f);
  float* o = qt + (b*6 + j)*QSn;
  o[t      ] = (v0 - mu)*rs*qng[t      ] + qnb[t      ];
  o[t + 256] = (v1 - mu)*rs*qng[t + 256] + qnb[t + 256];
  o[t + 512] = (v2 - mu)*rs*qng[t + 512] + qnb[t + 512];
}

// ---- pool (feat+pos)*(1-mask) 2x2 -> ATb[k=256][m=10880] bf16 (already /mp), invmp[m]
__global__ void k_pool(const float* f0, const float* p0, const void* m0,
                       const float* f1, const float* p1, const void* m1,
                       const float* f2, const float* p2, const void* m2,
                       const float* f3, const float* p3, const void* m3,
                       const int* __restrict__ det, __hip_bfloat16* ATb, float* invmp){
  int bx = blockIdx.x;
  int s = bx >> 11, b = (bx >> 8) & 7, c = bx & 255;
  const float* F; const float* Pp; const void* M; int H, SB;
  if (s == 0){ F=f0; Pp=p0; M=m0; H=64; SB=0;     }
  else if (s == 1){ F=f1; Pp=p1; M=m1; H=32; SB=8192;  }
  else if (s == 2){ F=f2; Pp=p2; M=m2; H=16; SB=10240; }
  else            { F=f3; Pp=p3; M=m3; H=8;  SB=10752; }
  int OW = H >> 1, T = OW * OW;
  int mode = (det[0] == 0) ? 0 : ((det[1] == 0) ? 2 : 1);
  const float* Fb = F + (size_t)(b*256 + c)*H*H;
  const float* Pb = Pp + (size_t)(b*256 + c)*H*H;
  int mbase = b*H*H;
  for (int tok = threadIdx.x; tok < T; tok += 256){
    int ph = tok / OW, pw = tok - ph*OW;
    int i00 = (ph*2)*H + pw*2;
    float xs = 0.f, msum = 0.f;
    #pragma unroll
    for (int dr = 0; dr < 2; ++dr){
      #pragma unroll
      for (int dc = 0; dc < 2; ++dc){
        int i = i00 + dr*H + dc;
        float mk;
        if (mode == 0)      mk = ((const int*)M)[mbase + i] ? 1.f : 0.f;
        else if (mode == 1) mk = ((const unsigned char*)M)[mbase + i] ? 1.f : 0.f;
        else                mk = ((const float*)M)[mbase + i];
        float w = 1.f - mk;
        xs += (Fb[i] + Pb[i]) * w;
        msum += w;
      }
    }
    float mp = fmaxf(msum * 0.25f, 1e-6f);
    float im = 1.f / mp;
    int mIdx = SB + b*T + tok;
    ATb[(size_t)c*MTOT + mIdx] = __float2bfloat16(xs * 0.25f * im);
    if (c == 0) invmp[mIdx] = im;
  }
}

// ---- convW (4 x [768][256] f32) -> Wb bf16 contiguous [s][n][k]
__global__ void k_wcvt(const float* cw0, const float* cw1, const float* cw2, const float* cw3,
                       __hip_bfloat16* Wb){
  int s = blockIdx.x / 192;
  int off = (blockIdx.x % 192)*1024 + threadIdx.x*4;
  const float* src = (s==0)?cw0:(s==1)?cw1:(s==2)?cw2:cw3;
  __hip_bfloat16* dst = Wb + (size_t)s*768*256;
  #pragma unroll
  for (int i = 0; i < 4; ++i) dst[off+i] = __float2bfloat16(src[off+i]);
}

// ---- transpose ATb[k][m] -> Am[m][k] (bf16), 64x64 tiles via LDS
__global__ void k_tr(const short* __restrict__ ATb, short* __restrict__ Am){
  __shared__ short lds[64][65];
  int mt = blockIdx.x >> 2, kt = blockIdx.x & 3;
  int m0 = mt*64, k0 = kt*64;
  int t = threadIdx.x;
  #pragma unroll
  for (int i = 0; i < 16; ++i){
    int idx = t + i*256;
    int k = idx >> 6, m = idx & 63;        // consecutive t -> consecutive m (coalesced read)
    lds[m][k] = ATb[(size_t)(k0+k)*MTOT + m0 + m];
  }
  __syncthreads();
  #pragma unroll
  for (int i = 0; i < 16; ++i){
    int idx = t + i*256;
    int m = idx >> 6, k = idx & 63;        // consecutive t -> consecutive k (coalesced write)
    Am[(size_t)(m0+m)*256 + k0 + k] = lds[m][k];
  }
}

// ---- fused bf16 MFMA GEMM + bias + LayerNorm + token-sum accumulation.
// 1 wave/block, tile = 16 m-rows x 768 n, K=256. Every 16-row block is (scale,batch)-pure.
// acc[48] float4 => rows m0..m0+15 fully in-register -> LN via shfl_xor, sum -> atomicAdd ctxsum.
__global__ __launch_bounds__(64, 1) void k_gemm_ln(
    const short* __restrict__ Am, const short* __restrict__ Wb,
    const float* __restrict__ invmp,
    const float* cb0, const float* cb1, const float* cb2, const float* cb3,
    const float* lg0, const float* lb0, const float* lg1, const float* lb1,
    const float* lg2, const float* lb2, const float* lg3, const float* lb3,
    float* __restrict__ ctxsum){
  int m0 = blockIdx.x * 16;
  int s, b;
  if (m0 < 8192){ s=0; b=m0>>10; }
  else if (m0 < 10240){ s=1; b=(m0-8192)>>8; }
  else if (m0 < 10752){ s=2; b=(m0-10240)>>6; }
  else { s=3; b=(m0-10752)>>4; }
  const float *CB, *LG, *LB;
  if (s==0){ CB=cb0; LG=lg0; LB=lb0; }
  else if (s==1){ CB=cb1; LG=lg1; LB=lb1; }
  else if (s==2){ CB=cb2; LG=lg2; LB=lb2; }
  else { CB=cb3; LG=lg3; LB=lb3; }

  int l = threadIdx.x;
  int lm = l & 15, lk = l >> 4;            // A: row=lm, k-group=lk ; B: col=lm, k-group=lk
  const short* Arow  = Am + (size_t)(m0 + lm)*256 + lk*8;
  const short* Bbase = Wb + (size_t)s*768*256 + (size_t)lm*256 + lk*8;

  float4v acc[48];
  #pragma unroll
  for (int nf = 0; nf < 48; ++nf) acc[nf] = (float4v){0.f,0.f,0.f,0.f};

  #pragma unroll 1
  for (int kc = 0; kc < 8; ++kc){
    short8 a = *(const short8*)(Arow + kc*32);
    const short* Bk = Bbase + kc*32;
    #pragma unroll
    for (int nf = 0; nf < 48; ++nf){
      short8 bf = *(const short8*)(Bk + (size_t)nf*16*256);
      acc[nf] = __builtin_amdgcn_mfma_f32_16x16x32_bf16(a, bf, acc[nf], 0, 0, 0);
    }
  }

  // ---- epilogue: P = acc + CB[n]*invmp[m]; per-row LN; sum over rows -> ctxsum[b]
  // D layout: col n = nf*16 + lm ; row m = m0 + lk*4 + reg
  float im[4];
  #pragma unroll
  for (int r = 0; r < 4; ++r) im[r] = invmp[m0 + lk*4 + r];

  float sum[4] = {0,0,0,0}, sq[4] = {0,0,0,0};
  #pragma unroll
  for (int nf = 0; nf < 48; ++nf){
    float cbv = CB[nf*16 + lm];
    #pragma unroll
    for (int r = 0; r < 4; ++r){
      float p = acc[nf][r] + cbv*im[r];
      acc[nf][r] = p;
      sum[r] += p;
      sq[r] = fmaf(p, p, sq[r]);
    }
  }
  float mu[4], rs[4];
  #pragma unroll
  for (int r = 0; r < 4; ++r){
    float sm = sum[r], ss = sq[r];
    #pragma unroll
    for (int off = 1; off < 16; off <<= 1){ sm += __shfl_xor(sm, off); ss += __shfl_xor(ss, off); }
    mu[r] = sm * (1.f/768.f);
    float var = ss * (1.f/768.f) - mu[r]*mu[r];
    rs[r] = rsqrtf(var + 1e-5f);
  }
  #pragma unroll
  for (int nf = 0; nf < 48; ++nf){
    int n = nf*16 + lm;
    float g = LG[n], bb = LB[n];
    float tv = 0.f;
    #pragma unroll
    for (int r = 0; r < 4; ++r) tv += (acc[nf][r] - mu[r]) * rs[r];
    tv = tv*g + 4.f*bb;                     // 4 rows of this lane-group
    tv += __shfl_xor(tv, 16);
    tv += __shfl_xor(tv, 32);               // now sum over all 16 rows
    if (lk == 0) atomicAdd(&ctxsum[b*768 + n], tv);
  }
}

// ---- v = qt0 + 0.2*sum(qt1..5) + 2*ctxsum/1360
__global__ void k_v(const float* __restrict__ qt, const float* __restrict__ ctxsum, float* v){
  int idx = blockIdx.x*256 + threadIdx.x;   // 6144
  int b = idx / 768, n = idx % 768;
  const float* q = qt + (size_t)b*6*768;
  float pm = q[768+n] + q[2*768+n] + q[3*768+n] + q[4*768+n] + q[5*768+n];
  v[idx] = q[n] + 0.2f*pm + 2.f*ctxsum[b*768 + n]*(1.f/1360.f);
}

// ---- h = relu(v @ W1 + b1)
__global__ void k_h(const float* __restrict__ v, const float* __restrict__ W1,
                    const float* __restrict__ b1, float* h){
  int idx = blockIdx.x*256 + threadIdx.x;   // 6144
  int b = idx / 768, o = idx % 768;
  const float* vb = v + b*768;
  float acc = b1[o];
  for (int c = 0; c < 768; ++c) acc = fmaf(vb[c], W1[c*768 + o], acc);
  h[idx] = fmaxf(acc, 0.f);
}

// ---- out = h @ W2 + b2
__global__ void k_out(const float* __restrict__ h, const float* __restrict__ W2,
                      const float* __restrict__ b2, float* out){
  int b = blockIdx.x, o = threadIdx.x;
  if (o >= 396) return;
  const float* hb = h + b*768;
  float acc = b2[o];
  for (int c = 0; c < 768; ++c) acc = fmaf(hb[c], W2[c*396 + o], acc);
  out[b*396 + o] = acc;
}

extern "C" void kernel_launch(void* const* d_in, const int* in_sizes, int n_in,
                              void* d_out, int out_size, void* d_ws, size_t ws_size,
                              hipStream_t stream){
  const float* pl = (const float*)d_in[0];
  const float* hs = (const float*)d_in[2];
  const float* feat[4]; const float* pos[4]; const void* mask[4];
  const float* cw[4]; const float* cb[4]; const float* lg[4]; const float* lb[4];
  for (int s = 0; s < 4; ++s){
    int base = 3 + 7*s;
    feat[s] = (const float*)d_in[base];
    pos[s]  = (const float*)d_in[base+1];
    mask[s] = d_in[base+2];
    cw[s]   = (const float*)d_in[base+3];
    cb[s]   = (const float*)d_in[base+4];
    lg[s]   = (const float*)d_in[base+5];
    lb[s]   = (const float*)d_in[base+6];
  }
  const float* lq  = (const float*)d_in[31];
  const float* Wq  = (const float*)d_in[32];
  const float* bq  = (const float*)d_in[33];
  const float* qng = (const float*)d_in[34];
  const float* qnb = (const float*)d_in[35];
  const float* W1  = (const float*)d_in[36];
  const float* b1  = (const float*)d_in[37];
  const float* W2  = (const float*)d_in[38];
  const float* b2  = (const float*)d_in[39];
  float* out = (float*)d_out;

  // ---- workspace layout (~12.9 MB)
  short* ATb    = (short*)d_ws;                       // 256*10880 bf16
  short* Am     = ATb + (size_t)256*MTOT;             // 10880*256 bf16
  short* Wb     = Am + (size_t)MTOT*256;              // 4*768*256 bf16
  float* invmp  = (float*)(Wb + (size_t)4*768*256);   // 10880 f32
  float* pooled = invmp + MTOT;                       // 40*256
  float* qt     = pooled + 40*RSn;                    // 8*6*768
  float* vv     = qt + Bn*6*QSn;                      // 8*768
  float* hh     = vv + Bn*QSn;                        // 8*768
  float* ctxsum = hh + Bn*QSn;                        // 8*768
  int*   det    = (int*)(ctxsum + Bn*QSn);            // 4 ints
  int*   flags  = det + 4;                            // 40 ints

  hipMemsetAsync(ctxsum, 0, Bn*QSn*sizeof(float) + 4*sizeof(int), stream);
  k_detect<<<32, 256, 0, stream>>>((const int*)mask[0], det);
  k_pooled<<<Bn*Pn, 256, 0, stream>>>(pl, hs, pooled, flags);
  k_qtok<<<Bn*6, 256, 0, stream>>>(lq, Wq, bq, qng, qnb, pooled, flags, qt);
  k_wcvt<<<4*192, 256, 0, stream>>>(cw[0], cw[1], cw[2], cw[3], (__hip_bfloat16*)Wb);
  k_pool<<<8192, 256, 0, stream>>>(feat[0], pos[0], mask[0],
                                   feat[1], pos[1], mask[1],
                                   feat[2], pos[2], mask[2],
                                   feat[3], pos[3], mask[3],
                                   det, (__hip_bfloat16*)ATb, invmp);
  k_tr<<<170*4, 256, 0, stream>>>(ATb, Am);
  k_gemm_ln<<<MTOT/16, 64, 0, stream>>>(Am, Wb, invmp,
                                        cb[0], cb[1], cb[2], cb[3],
                                        lg[0], lb[0], lg[1], lb[1],
                                        lg[2], lb[2], lg[3], lb[3], ctxsum);
  k_v<<<24, 256, 0, stream>>>(qt, ctxsum, vv);
  k_h<<<24, 256, 0, stream>>>(vv, W1, b1, hh);
  k_out<<<Bn, 512, 0, stream>>>(hh, W2, b2, out);
}

// Round 3
// 348.477 us; speedup vs baseline: 1.4460x; 1.0897x over previous
//
#include <hip/hip_runtime.h>
#include <hip/hip_bf16.h>

#define Bn 8
#define Qn 300
#define Pn 5
#define RSn 256
#define QSn 768
#define MTOT 10880
#define THRL -1.3862943611198906f   // log(0.2/0.8): sigmoid(x)>0.2 <=> x>THRL

typedef __attribute__((ext_vector_type(8))) short short8;
typedef __attribute__((ext_vector_type(4))) float float4v;

__device__ inline float wred(float v){
  #pragma unroll
  for (int off = 32; off; off >>= 1) v += __shfl_xor(v, off);
  return v;
}

// ---- fused: convW f32 -> bf16 [s][n][k] (blocks 0..767)  +  mask-mode detect (blocks 768..799)
__global__ void k_prep(const float* cw0, const float* cw1, const float* cw2, const float* cw3,
                       __hip_bfloat16* Wb, const int* __restrict__ m0, int* det){
  if (blockIdx.x >= 768){
    int i = (blockIdx.x - 768) * 256 + threadIdx.x;   // 8192 ints = 32KB, safe under all layouts
    int v = m0[i];
    if (v != 0 && v != 1) atomicOr(&det[0], 1);
    if (v != 0 && v != 0x3F800000) atomicOr(&det[1], 1);
    return;
  }
  int s = blockIdx.x / 192;
  int off = (blockIdx.x % 192)*1024 + threadIdx.x*4;
  const float* src = (s==0)?cw0:(s==1)?cw1:(s==2)?cw2:cw3;
  __hip_bfloat16* dst = Wb + (size_t)s*768*256;
  #pragma unroll
  for (int i = 0; i < 4; ++i) dst[off+i] = __float2bfloat16(src[off+i]);
}

// ---- query pooling: pooled[b,p,:], flags[b,p] = cnt>0
__global__ void k_pooled(const float* __restrict__ pl, const float* __restrict__ hs,
                         float* pooled, int* flags){
  __shared__ float msk[Qn];
  int b = blockIdx.x / Pn, p = blockIdx.x % Pn;
  int t = threadIdx.x;
  for (int q = t; q < Qn; q += 256)
    msk[q] = (pl[(b*Qn + q)*Pn + p] > THRL) ? 1.f : 0.f;
  __syncthreads();
  const float* hb = hs + (size_t)b*Qn*RSn + t;
  float ssum = 0.f, cnt = 0.f;
  for (int q = 0; q < Qn; ++q){
    float m = msk[q];
    cnt += m;
    ssum = fmaf(m, hb[(size_t)q*RSn], ssum);
  }
  pooled[(b*Pn + p)*RSn + t] = (cnt > 0.f) ? ssum / cnt : 0.f;
  if (t == 0) flags[b*Pn + p] = (cnt > 0.f) ? 1 : 0;
}

// ---- query tokens + LN -> qt[b,6,768]
__global__ void k_qtok(const float* __restrict__ lq, const float* __restrict__ Wq,
                       const float* __restrict__ bq, const float* __restrict__ qng,
                       const float* __restrict__ qnb, const float* __restrict__ pooled,
                       const int* __restrict__ flags, float* qt){
  __shared__ float s1[4], s2[4];
  int b = blockIdx.x / 6, j = blockIdx.x % 6;
  int t = threadIdx.x;
  float v0 = lq[j*QSn + t], v1 = lq[j*QSn + t + 256], v2 = lq[j*QSn + t + 512];
  int any = flags[b*Pn] | flags[b*Pn+1] | flags[b*Pn+2] | flags[b*Pn+3] | flags[b*Pn+4];
  if (j > 0 && any){
    const float* pp = pooled + (b*Pn + (j-1))*RSn;
    float a0 = 0.f, a1 = 0.f, a2 = 0.f;
    for (int c = 0; c < RSn; ++c){
      float pv = pp[c];
      a0 = fmaf(pv, Wq[c*QSn + t      ], a0);
      a1 = fmaf(pv, Wq[c*QSn + t + 256], a1);
      a2 = fmaf(pv, Wq[c*QSn + t + 512], a2);
    }
    v0 += a0 + bq[t]; v1 += a1 + bq[t+256]; v2 += a2 + bq[t+512];
  }
  float sm = v0 + v1 + v2, sq = v0*v0 + v1*v1 + v2*v2;
  sm = wred(sm); sq = wred(sq);
  int wid = t >> 6, lane = t & 63;
  if (lane == 0){ s1[wid] = sm; s2[wid] = sq; }
  __syncthreads();
  float S  = s1[0] + s1[1] + s1[2] + s1[3];
  float SQ = s2[0] + s2[1] + s2[2] + s2[3];
  float mu = S * (1.f/QSn), var = SQ * (1.f/QSn) - mu*mu;
  float rs = rsqrtf(var + 1e-5f);
  float* o = qt + (b*6 + j)*QSn;
  o[t      ] = (v0 - mu)*rs*qng[t      ] + qnb[t      ];
  o[t + 256] = (v1 - mu)*rs*qng[t + 256] + qnb[t + 256];
  o[t + 512] = (v2 - mu)*rs*qng[t + 512] + qnb[t + 512];
}

// ---- pool (feat+pos)*(1-mask) 2x2 -> ATb[k=256][m=10880] bf16 (already /mp), invmp[m]
__global__ void k_pool(const float* f0, const float* p0, const void* m0,
                       const float* f1, const float* p1, const void* m1,
                       const float* f2, const float* p2, const void* m2,
                       const float* f3, const float* p3, const void* m3,
                       const int* __restrict__ det, __hip_bfloat16* ATb, float* invmp){
  int bx = blockIdx.x;
  int s = bx >> 11, b = (bx >> 8) & 7, c = bx & 255;
  const float* F; const float* Pp; const void* M; int H, SB;
  if (s == 0){ F=f0; Pp=p0; M=m0; H=64; SB=0;     }
  else if (s == 1){ F=f1; Pp=p1; M=m1; H=32; SB=8192;  }
  else if (s == 2){ F=f2; Pp=p2; M=m2; H=16; SB=10240; }
  else            { F=f3; Pp=p3; M=m3; H=8;  SB=10752; }
  int OW = H >> 1, T = OW * OW;
  int mode = (det[0] == 0) ? 0 : ((det[1] == 0) ? 2 : 1);
  const float* Fb = F + (size_t)(b*256 + c)*H*H;
  const float* Pb = Pp + (size_t)(b*256 + c)*H*H;
  int mbase = b*H*H;
  for (int tok = threadIdx.x; tok < T; tok += 256){
    int ph = tok / OW, pw = tok - ph*OW;
    int i00 = (ph*2)*H + pw*2;
    float2 fa = *(const float2*)(Fb + i00);
    float2 fb2 = *(const float2*)(Fb + i00 + H);
    float2 pa = *(const float2*)(Pb + i00);
    float2 pb2 = *(const float2*)(Pb + i00 + H);
    float w00, w01, w10, w11;
    if (mode == 0){
      int2 ma = *(const int2*)((const int*)M + mbase + i00);
      int2 mb = *(const int2*)((const int*)M + mbase + i00 + H);
      w00 = ma.x ? 0.f : 1.f; w01 = ma.y ? 0.f : 1.f;
      w10 = mb.x ? 0.f : 1.f; w11 = mb.y ? 0.f : 1.f;
    } else if (mode == 1){
      const unsigned char* Mb = (const unsigned char*)M + mbase;
      w00 = Mb[i00] ? 0.f : 1.f;   w01 = Mb[i00+1] ? 0.f : 1.f;
      w10 = Mb[i00+H] ? 0.f : 1.f; w11 = Mb[i00+H+1] ? 0.f : 1.f;
    } else {
      float2 ma = *(const float2*)((const float*)M + mbase + i00);
      float2 mb = *(const float2*)((const float*)M + mbase + i00 + H);
      w00 = 1.f - ma.x; w01 = 1.f - ma.y;
      w10 = 1.f - mb.x; w11 = 1.f - mb.y;
    }
    float xs = (fa.x + pa.x)*w00 + (fa.y + pa.y)*w01
             + (fb2.x + pb2.x)*w10 + (fb2.y + pb2.y)*w11;
    float msum = w00 + w01 + w10 + w11;
    float mp = fmaxf(msum * 0.25f, 1e-6f);
    float im = 1.f / mp;
    int mIdx = SB + b*T + tok;
    ATb[(size_t)c*MTOT + mIdx] = __float2bfloat16(xs * 0.25f * im);
    if (c == 0) invmp[mIdx] = im;
  }
}

// ---- transpose ATb[k][m] -> Am[m][k] (bf16), 64x64 tiles via LDS
__global__ void k_tr(const short* __restrict__ ATb, short* __restrict__ Am){
  __shared__ short lds[64][65];
  int mt = blockIdx.x >> 2, kt = blockIdx.x & 3;
  int m0 = mt*64, k0 = kt*64;
  int t = threadIdx.x;
  #pragma unroll
  for (int i = 0; i < 16; ++i){
    int idx = t + i*256;
    int k = idx >> 6, m = idx & 63;
    lds[m][k] = ATb[(size_t)(k0+k)*MTOT + m0 + m];
  }
  __syncthreads();
  #pragma unroll
  for (int i = 0; i < 16; ++i){
    int idx = t + i*256;
    int m = idx >> 6, k = idx & 63;
    Am[(size_t)(m0+m)*256 + k0 + k] = lds[m][k];
  }
}

// ---- fused bf16 MFMA GEMM + bias + LayerNorm + token-sum accumulation.
// 256 threads = 4 waves; block tile = 16 m-rows x 768 n, n split 4-ways (12 frags/wave).
// K=256 via mfma_f32_16x16x32_bf16, no LDS for operands; LN stats combined via 1KB LDS.
__global__ __launch_bounds__(256, 3) void k_gemm_ln(
    const short* __restrict__ Am, const short* __restrict__ Wb,
    const float* __restrict__ invmp,
    const float* cb0, const float* cb1, const float* cb2, const float* cb3,
    const float* lg0, const float* lb0, const float* lg1, const float* lb1,
    const float* lg2, const float* lb2, const float* lg3, const float* lb3,
    float* __restrict__ ctxsum){
  __shared__ float lsum[4][16], lsq[4][16];
  int m0 = blockIdx.x * 16;
  int s, b;
  if (m0 < 8192){ s=0; b=m0>>10; }
  else if (m0 < 10240){ s=1; b=(m0-8192)>>8; }
  else if (m0 < 10752){ s=2; b=(m0-10240)>>6; }
  else { s=3; b=(m0-10752)>>4; }
  const float *CB, *LG, *LB;
  if (s==0){ CB=cb0; LG=lg0; LB=lb0; }
  else if (s==1){ CB=cb1; LG=lg1; LB=lb1; }
  else if (s==2){ CB=cb2; LG=lg2; LB=lb2; }
  else { CB=cb3; LG=lg3; LB=lb3; }

  int t = threadIdx.x;
  int wid = t >> 6, l = t & 63;
  int lm = l & 15, lk = l >> 4;            // A: row=lm ; B: col=lm ; k-group=lk
  int nfb = wid * 12;                      // this wave's frag range [nfb, nfb+12)
  const short* Arow  = Am + (size_t)(m0 + lm)*256 + lk*8;
  const short* Bbase = Wb + (size_t)s*768*256 + (size_t)(nfb*16 + lm)*256 + lk*8;

  float4v acc[12];
  #pragma unroll
  for (int nf = 0; nf < 12; ++nf) acc[nf] = (float4v){0.f,0.f,0.f,0.f};

  #pragma unroll 1
  for (int kc = 0; kc < 8; ++kc){
    short8 a = *(const short8*)(Arow + kc*32);
    const short* Bk = Bbase + kc*32;
    short8 bfr[12];
    #pragma unroll
    for (int nf = 0; nf < 12; ++nf)
      bfr[nf] = *(const short8*)(Bk + (size_t)nf*16*256);
    #pragma unroll
    for (int nf = 0; nf < 12; ++nf)
      acc[nf] = __builtin_amdgcn_mfma_f32_16x16x32_bf16(a, bfr[nf], acc[nf], 0, 0, 0);
  }

  // ---- bias + partial LN stats (this wave's 192 of 768 cols)
  // D layout: col n = (nfb+nf)*16 + lm ; row m = m0 + lk*4 + reg
  float im[4];
  #pragma unroll
  for (int r = 0; r < 4; ++r) im[r] = invmp[m0 + lk*4 + r];

  float sum[4] = {0,0,0,0}, sq[4] = {0,0,0,0};
  #pragma unroll
  for (int nf = 0; nf < 12; ++nf){
    float cbv = CB[(nfb+nf)*16 + lm];
    #pragma unroll
    for (int r = 0; r < 4; ++r){
      float p = acc[nf][r] + cbv*im[r];
      acc[nf][r] = p;
      sum[r] += p;
      sq[r] = fmaf(p, p, sq[r]);
    }
  }
  #pragma unroll
  for (int r = 0; r < 4; ++r){
    #pragma unroll
    for (int off = 1; off < 16; off <<= 1){
      sum[r] += __shfl_xor(sum[r], off);
      sq[r]  += __shfl_xor(sq[r],  off);
    }
  }
  if (lm == 0){
    #pragma unroll
    for (int r = 0; r < 4; ++r){ lsum[wid][lk*4+r] = sum[r]; lsq[wid][lk*4+r] = sq[r]; }
  }
  __syncthreads();
  float mu[4], rs[4];
  #pragma unroll
  for (int r = 0; r < 4; ++r){
    int row = lk*4 + r;
    float S  = lsum[0][row] + lsum[1][row] + lsum[2][row] + lsum[3][row];
    float SQ = lsq[0][row]  + lsq[1][row]  + lsq[2][row]  + lsq[3][row];
    mu[r] = S * (1.f/768.f);
    float var = SQ * (1.f/768.f) - mu[r]*mu[r];
    rs[r] = rsqrtf(var + 1e-5f);
  }
  // ---- normalize, scale, sum over 16 rows, accumulate
  #pragma unroll
  for (int nf = 0; nf < 12; ++nf){
    int n = (nfb+nf)*16 + lm;
    float g = LG[n], bb = LB[n];
    float tv = 0.f;
    #pragma unroll
    for (int r = 0; r < 4; ++r) tv += (acc[nf][r] - mu[r]) * rs[r];
    tv = tv*g + 4.f*bb;                     // 4 rows of this lane-group
    tv += __shfl_xor(tv, 16);
    tv += __shfl_xor(tv, 32);               // now sum over all 16 rows
    if (lk == 0) atomicAdd(&ctxsum[b*768 + n], tv);
  }
}

// ---- v = qt0 + 0.2*sum(qt1..5) + 2*ctxsum/1360
__global__ void k_v(const float* __restrict__ qt, const float* __restrict__ ctxsum, float* v){
  int idx = blockIdx.x*256 + threadIdx.x;   // 6144
  int b = idx / 768, n = idx % 768;
  const float* q = qt + (size_t)b*6*768;
  float pm = q[768+n] + q[2*768+n] + q[3*768+n] + q[4*768+n] + q[5*768+n];
  v[idx] = q[n] + 0.2f*pm + 2.f*ctxsum[b*768 + n]*(1.f/1360.f);
}

// ---- h = relu(v @ W1 + b1)
__global__ void k_h(const float* __restrict__ v, const float* __restrict__ W1,
                    const float* __restrict__ b1, float* h){
  int idx = blockIdx.x*256 + threadIdx.x;   // 6144
  int b = idx / 768, o = idx % 768;
  const float* vb = v + b*768;
  float acc = b1[o];
  for (int c = 0; c < 768; ++c) acc = fmaf(vb[c], W1[c*768 + o], acc);
  h[idx] = fmaxf(acc, 0.f);
}

// ---- out = h @ W2 + b2
__global__ void k_out(const float* __restrict__ h, const float* __restrict__ W2,
                      const float* __restrict__ b2, float* out){
  int b = blockIdx.x, o = threadIdx.x;
  if (o >= 396) return;
  const float* hb = h + b*768;
  float acc = b2[o];
  for (int c = 0; c < 768; ++c) acc = fmaf(hb[c], W2[c*396 + o], acc);
  out[b*396 + o] = acc;
}

extern "C" void kernel_launch(void* const* d_in, const int* in_sizes, int n_in,
                              void* d_out, int out_size, void* d_ws, size_t ws_size,
                              hipStream_t stream){
  const float* pl = (const float*)d_in[0];
  const float* hs = (const float*)d_in[2];
  const float* feat[4]; const float* pos[4]; const void* mask[4];
  const float* cw[4]; const float* cb[4]; const float* lg[4]; const float* lb[4];
  for (int s = 0; s < 4; ++s){
    int base = 3 + 7*s;
    feat[s] = (const float*)d_in[base];
    pos[s]  = (const float*)d_in[base+1];
    mask[s] = d_in[base+2];
    cw[s]   = (const float*)d_in[base+3];
    cb[s]   = (const float*)d_in[base+4];
    lg[s]   = (const float*)d_in[base+5];
    lb[s]   = (const float*)d_in[base+6];
  }
  const float* lq  = (const float*)d_in[31];
  const float* Wq  = (const float*)d_in[32];
  const float* bq  = (const float*)d_in[33];
  const float* qng = (const float*)d_in[34];
  const float* qnb = (const float*)d_in[35];
  const float* W1  = (const float*)d_in[36];
  const float* b1  = (const float*)d_in[37];
  const float* W2  = (const float*)d_in[38];
  const float* b2  = (const float*)d_in[39];
  float* out = (float*)d_out;

  // ---- workspace layout (~12.9 MB)
  short* ATb    = (short*)d_ws;                       // 256*10880 bf16
  short* Am     = ATb + (size_t)256*MTOT;             // 10880*256 bf16
  short* Wb     = Am + (size_t)MTOT*256;              // 4*768*256 bf16
  float* invmp  = (float*)(Wb + (size_t)4*768*256);   // 10880 f32
  float* pooled = invmp + MTOT;                       // 40*256
  float* qt     = pooled + 40*RSn;                    // 8*6*768
  float* vv     = qt + Bn*6*QSn;                      // 8*768
  float* hh     = vv + Bn*QSn;                        // 8*768
  float* ctxsum = hh + Bn*QSn;                        // 8*768
  int*   det    = (int*)(ctxsum + Bn*QSn);            // 4 ints
  int*   flags  = det + 4;                            // 40 ints

  hipMemsetAsync(ctxsum, 0, Bn*QSn*sizeof(float) + 4*sizeof(int), stream);
  k_prep<<<800, 256, 0, stream>>>(cw[0], cw[1], cw[2], cw[3], (__hip_bfloat16*)Wb,
                                  (const int*)mask[0], det);
  k_pooled<<<Bn*Pn, 256, 0, stream>>>(pl, hs, pooled, flags);
  k_qtok<<<Bn*6, 256, 0, stream>>>(lq, Wq, bq, qng, qnb, pooled, flags, qt);
  k_pool<<<8192, 256, 0, stream>>>(feat[0], pos[0], mask[0],
                                   feat[1], pos[1], mask[1],
                                   feat[2], pos[2], mask[2],
                                   feat[3], pos[3], mask[3],
                                   det, (__hip_bfloat16*)ATb, invmp);
  k_tr<<<170*4, 256, 0, stream>>>(ATb, Am);
  k_gemm_ln<<<MTOT/16, 256, 0, stream>>>(Am, Wb, invmp,
                                         cb[0], cb[1], cb[2], cb[3],
                                         lg[0], lb[0], lg[1], lb[1],
                                         lg[2], lb[2], lg[3], lb[3], ctxsum);
  k_v<<<24, 256, 0, stream>>>(qt, ctxsum, vv);
  k_h<<<24, 256, 0, stream>>>(vv, W1, b1, hh);
  k_out<<<Bn, 512, 0, stream>>>(hh, W2, b2, out);
}